// Round 8
// baseline (7444.944 us; speedup 1.0000x reference)
//
#include <hip/hip_runtime.h>

#define D 64
#define EPS 0.006f
#define KSPLIT 2

typedef __attribute__((ext_vector_type(8))) short bf16x8;
typedef __attribute__((ext_vector_type(4))) float f32x4;

// RNE fp32 -> bf16 (bit trick; matches HW cvt for normal values)
static __device__ __forceinline__ short f2bf(float x) {
    unsigned u = __float_as_uint(x);
    unsigned r = u + 0x7fff + ((u >> 16) & 1);
    return (short)(r >> 16);
}
static __device__ __forceinline__ float bf2f(short s) {
    return __uint_as_float(((unsigned)(unsigned short)s) << 16);
}

// Fused: centroid fp32 -> (hi,lo) bf16 split + c2 row norms + counter zero.
__global__ void prep_kernel(const float* __restrict__ c, short* __restrict__ ch,
                            short* __restrict__ cl, float* __restrict__ c2,
                            int K, int* __restrict__ counter) {
    int t = blockIdx.x * blockDim.x + threadIdx.x;
    if (t == 0) *counter = 0;
    const int nf4 = K * (D / 4);
    if (t < nf4) {
        float4 v = ((const float4*)c)[t];
        short hx = f2bf(v.x), hy = f2bf(v.y), hz = f2bf(v.z), hw = f2bf(v.w);
        ((short4*)ch)[t] = make_short4(hx, hy, hz, hw);
        ((short4*)cl)[t] = make_short4(f2bf(v.x - bf2f(hx)), f2bf(v.y - bf2f(hy)),
                                       f2bf(v.z - bf2f(hz)), f2bf(v.w - bf2f(hw)));
    }
    if (t < K) {
        const float4* cp = (const float4*)(c + (size_t)t * D);
        float s = 0.f;
#pragma unroll
        for (int i = 0; i < D / 4; ++i) {
            float4 v = cp[i];
            s += v.x * v.x; s += v.y * v.y; s += v.z * v.z; s += v.w * v.w;
        }
        c2[t] = s;
    }
}

// Pass 1: split-bf16 MFMA distance scan, top-2 tracking, K split over
// blockIdx.y. Depth-2 register prefetch ring on B loads (~320 cyc coverage
// >= L2 latency; round-7's depth-1 left a per-iter vmcnt stall).
// score(n,k) = c2[k] - 2*dot(a,c); dot ~= ah.ch + ah.cl + al.ch
__global__ __launch_bounds__(256, 4) void pass1_kernel(
    const float* __restrict__ action, const short* __restrict__ ch,
    const short* __restrict__ cl, const float* __restrict__ c2,
    float4* __restrict__ cand, int N, int K) {
    const int tid  = threadIdx.x;
    const int wv   = tid >> 6;
    const int lane = tid & 63;
    const int col  = lane & 15;
    const int quad = lane >> 4;
    const int m0   = blockIdx.x * 128 + wv * 32;
    const int KC   = K / KSPLIT;
    const int k0   = blockIdx.y * KC;

    // A fragments: fp32 -> (hi, lo) bf16 in registers, once.
    bf16x8 ah[2][2], al[2][2];
#pragma unroll
    for (int mi = 0; mi < 2; ++mi) {
        const float* arow = action + (size_t)(m0 + mi * 16 + col) * D;
#pragma unroll
        for (int ks = 0; ks < 2; ++ks) {
            const float* src = arow + ks * 32 + quad * 8;
            bf16x8 h, l;
#pragma unroll
            for (int j = 0; j < 8; ++j) {
                float x = src[j];
                short hs = f2bf(x);
                h[j] = hs;
                l[j] = f2bf(x - bf2f(hs));
            }
            ah[mi][ks] = h;
            al[mi][ks] = l;
        }
    }

    float b1[8], b2[8];
    int   bk[8];
#pragma unroll
    for (int e = 0; e < 8; ++e) {
        b1[e] = __builtin_inff(); b2[e] = __builtin_inff(); bk[e] = k0;
    }

    const int T = KC / 16;   // iterations (64)

    // depth-2 prefetch ring
    bf16x8 pb[2][4];
    float  pcc[2];
#pragma unroll
    for (int i = 0; i < 2; ++i) {
        const int kk = k0 + i * 16 + col;
        const size_t kb = (size_t)kk * D + quad * 8;
        pb[i][0] = *(const bf16x8*)(ch + kb);
        pb[i][1] = *(const bf16x8*)(ch + kb + 32);
        pb[i][2] = *(const bf16x8*)(cl + kb);
        pb[i][3] = *(const bf16x8*)(cl + kb + 32);
        pcc[i]   = c2[kk];
    }

#pragma unroll 2
    for (int i = 0; i < T; ++i) {
        const int slot = i & 1;
        bf16x8 bh0 = pb[slot][0], bh1 = pb[slot][1];
        bf16x8 bl0 = pb[slot][2], bl1 = pb[slot][3];
        const float cc = pcc[slot];
        const int   k  = k0 + i * 16 + col;

        if (i + 2 < T) {
            const int kk = k0 + (i + 2) * 16 + col;
            const size_t kb = (size_t)kk * D + quad * 8;
            pb[slot][0] = *(const bf16x8*)(ch + kb);
            pb[slot][1] = *(const bf16x8*)(ch + kb + 32);
            pb[slot][2] = *(const bf16x8*)(cl + kb);
            pb[slot][3] = *(const bf16x8*)(cl + kb + 32);
            pcc[slot]   = c2[kk];
        }

#pragma unroll
        for (int mi = 0; mi < 2; ++mi) {
            f32x4 acc = {0.f, 0.f, 0.f, 0.f};
            acc = __builtin_amdgcn_mfma_f32_16x16x32_bf16(al[mi][0], bh0, acc, 0, 0, 0);
            acc = __builtin_amdgcn_mfma_f32_16x16x32_bf16(ah[mi][0], bl0, acc, 0, 0, 0);
            acc = __builtin_amdgcn_mfma_f32_16x16x32_bf16(ah[mi][0], bh0, acc, 0, 0, 0);
            acc = __builtin_amdgcn_mfma_f32_16x16x32_bf16(al[mi][1], bh1, acc, 0, 0, 0);
            acc = __builtin_amdgcn_mfma_f32_16x16x32_bf16(ah[mi][1], bl1, acc, 0, 0, 0);
            acc = __builtin_amdgcn_mfma_f32_16x16x32_bf16(ah[mi][1], bh1, acc, 0, 0, 0);
#pragma unroll
            for (int r = 0; r < 4; ++r) {
                const int e = mi * 4 + r;
                const float s = fmaf(-2.f, acc[r], cc);
                // b2' = median(s, b1, b2) == fmin(b2, fmax(s, b1)) since b1<=b2
                b2[e] = __builtin_amdgcn_fmed3f(s, b1[e], b2[e]);
                const bool better = s < b1[e];          // strict <: first-min
                b1[e] = fminf(b1[e], s);
                bk[e] = better ? k : bk[e];
            }
        }
    }

    // cross-lane top-2 merge over the 16 centroid columns
#pragma unroll
    for (int off = 1; off < 16; off <<= 1) {
#pragma unroll
        for (int e = 0; e < 8; ++e) {
            float o1 = __shfl_xor(b1[e], off, 64);
            float o2 = __shfl_xor(b2[e], off, 64);
            int   ok = __shfl_xor(bk[e], off, 64);
            bool take = (o1 < b1[e]) || (o1 == b1[e] && ok < bk[e]);
            float nb2 = take ? fminf(b1[e], o2) : fminf(b2[e], o1);
            b1[e] = take ? o1 : b1[e];
            bk[e] = take ? ok : bk[e];
            b2[e] = nb2;
        }
    }

    if (col == 0) {
#pragma unroll
        for (int e = 0; e < 8; ++e) {
            const int mi = e >> 2, r = e & 3;
            const int p = m0 + mi * 16 + quad * 4 + r;
            cand[(size_t)blockIdx.y * N + p] =
                make_float4(b1[e], b2[e], (float)bk[e], 0.f);
        }
    }
}

// Fused merge + bin write + ambiguity flag + exact fp32 residual.
// Split0 owns lower k, so strict < keeps split0 on ties = numpy first-min.
__global__ __launch_bounds__(256) void resflag_kernel(
    const float* __restrict__ action, const float* __restrict__ centroids,
    const float4* __restrict__ cand, float* __restrict__ out_bin,
    float* __restrict__ out_res, int* __restrict__ counter,
    int* __restrict__ flags, int N) {
    int n = blockIdx.x * blockDim.x + threadIdx.x;
    if (n >= N) return;
    float4 v0 = cand[n];
    float4 v1 = cand[(size_t)N + n];
    float b1, b2; int bk;
    if (v1.x < v0.x) { b1 = v1.x; bk = (int)v1.z; b2 = fminf(v0.x, v1.y); }
    else             { b1 = v0.x; bk = (int)v0.z; b2 = fminf(v1.x, v0.y); }
    out_bin[n] = (float)bk;
    if (b2 - b1 < EPS) {
        int idx = atomicAdd(counter, 1);
        flags[idx] = n;
    }
    const float4* ap = (const float4*)(action + (size_t)n * D);
    const float4* cp = (const float4*)(centroids + (size_t)bk * D);
    float4*       rp = (float4*)(out_res + (size_t)n * D);
#pragma unroll
    for (int i = 0; i < D / 4; ++i) {
        float4 a = ap[i], c = cp[i];
        rp[i] = make_float4(a.x - c.x, a.y - c.y, a.z - c.z, a.w - c.w);
    }
}

// Exact fp32 rescan for flagged points. Block-per-point grid-stride
// (round-6 structure: high TLP), 4 interleaved dot accumulators for ILP.
// Ascending k strict < per thread + lexicographic merge = numpy first-min.
__global__ __launch_bounds__(256) void exact_kernel(
    const float* __restrict__ action, const float* __restrict__ centroids,
    const float* __restrict__ c2, const int* __restrict__ counter,
    const int* __restrict__ flags, float* __restrict__ out_bin,
    float* __restrict__ out_res, int K) {
    __shared__ float4 sa[D / 4];
    __shared__ float  swv[4];
    __shared__ int    swk[4];
    __shared__ int    s_bk;
    const int count = *counter;
    const int tid = threadIdx.x, lane = tid & 63, wid = tid >> 6;
    for (int i = blockIdx.x; i < count; i += gridDim.x) {
        const int n = flags[i];
        __syncthreads();
        if (tid < D / 4) sa[tid] = ((const float4*)(action + (size_t)n * D))[tid];
        __syncthreads();
        float best = __builtin_inff();
        int bbk = 0x7fffffff;
        for (int k = tid; k < K; k += 256) {
            const float4* cr = (const float4*)(centroids + (size_t)k * D);
            float d0 = 0.f, d1 = 0.f, d2 = 0.f, d3 = 0.f;
#pragma unroll
            for (int q = 0; q < 4; ++q) {
                float4 a0 = sa[q * 4 + 0], c0 = cr[q * 4 + 0];
                float4 a1 = sa[q * 4 + 1], c1 = cr[q * 4 + 1];
                float4 a2 = sa[q * 4 + 2], c2v = cr[q * 4 + 2];
                float4 a3 = sa[q * 4 + 3], c3 = cr[q * 4 + 3];
                d0 = fmaf(a0.x, c0.x, d0); d0 = fmaf(a0.y, c0.y, d0);
                d0 = fmaf(a0.z, c0.z, d0); d0 = fmaf(a0.w, c0.w, d0);
                d1 = fmaf(a1.x, c1.x, d1); d1 = fmaf(a1.y, c1.y, d1);
                d1 = fmaf(a1.z, c1.z, d1); d1 = fmaf(a1.w, c1.w, d1);
                d2 = fmaf(a2.x, c2v.x, d2); d2 = fmaf(a2.y, c2v.y, d2);
                d2 = fmaf(a2.z, c2v.z, d2); d2 = fmaf(a2.w, c2v.w, d2);
                d3 = fmaf(a3.x, c3.x, d3); d3 = fmaf(a3.y, c3.y, d3);
                d3 = fmaf(a3.z, c3.z, d3); d3 = fmaf(a3.w, c3.w, d3);
            }
            float dot = (d0 + d1) + (d2 + d3);
            float s = fmaf(-2.f, dot, c2[k]);
            if (s < best) { best = s; bbk = k; }  // ascending k: first-min
        }
        // wave reduce with (score, index) lexicographic tie-break
#pragma unroll
        for (int off = 32; off > 0; off >>= 1) {
            float ov = __shfl_down(best, off, 64);
            int   ok = __shfl_down(bbk, off, 64);
            if (ov < best || (ov == best && ok < bbk)) { best = ov; bbk = ok; }
        }
        if (lane == 0) { swv[wid] = best; swk[wid] = bbk; }
        __syncthreads();
        if (tid == 0) {
            float bb = swv[0]; int bki = swk[0];
#pragma unroll
            for (int t = 1; t < 4; ++t)
                if (swv[t] < bb || (swv[t] == bb && swk[t] < bki)) {
                    bb = swv[t]; bki = swk[t];
                }
            out_bin[n] = (float)bki;
            s_bk = bki;
        }
        __syncthreads();
        if (tid < D / 4) {
            float4 a = sa[tid];
            float4 c = ((const float4*)(centroids + (size_t)s_bk * D))[tid];
            ((float4*)(out_res + (size_t)n * D))[tid] =
                make_float4(a.x - c.x, a.y - c.y, a.z - c.z, a.w - c.w);
        }
    }
}

extern "C" void kernel_launch(void* const* d_in, const int* in_sizes, int n_in,
                              void* d_out, int out_size, void* d_ws, size_t ws_size,
                              hipStream_t stream) {
    const float* action    = (const float*)d_in[0];  // [N, 64]
    const float* centroids = (const float*)d_in[1];  // [K, 64]
    const int N = in_sizes[0] / D;  // 65536
    const int K = in_sizes[1] / D;  // 2048

    float* out_bin = (float*)d_out;      // N floats: argmin index
    float* out_res = (float*)d_out + N;  // N*D residuals

    // ws layout (~2.9 MB)
    char* w = (char*)d_ws;
    float*  c2      = (float*)w;                       // 8 KB
    int*    counter = (int*)(w + 8192);                // 4 B (padded to 256)
    int*    flags   = (int*)(w + 8448);                // N*4 = 256 KB
    short*  ch      = (short*)(w + 8448 + 262144);     // K*D*2 = 256 KB
    short*  cl      = ch + (size_t)K * D;              // 256 KB
    float4* cand    = (float4*)(cl + (size_t)K * D);   // KSPLIT*N*16 = 2 MB

    prep_kernel<<<(K * (D / 4) + 255) / 256, 256, 0, stream>>>(centroids, ch, cl,
                                                               c2, K, counter);
    dim3 g1(N / 128, KSPLIT);
    pass1_kernel<<<g1, 256, 0, stream>>>(action, ch, cl, c2, cand, N, K);
    resflag_kernel<<<(N + 255) / 256, 256, 0, stream>>>(action, centroids, cand,
                                                        out_bin, out_res, counter,
                                                        flags, N);
    exact_kernel<<<2048, 256, 0, stream>>>(action, centroids, c2, counter, flags,
                                           out_bin, out_res, K);
}

// Round 9
// 311.733 us; speedup vs baseline: 23.8824x; 23.8824x over previous
//
#include <hip/hip_runtime.h>

#define D 64
#define EPS 0.006f
#define KSPLIT 2

typedef __attribute__((ext_vector_type(8))) short bf16x8;
typedef __attribute__((ext_vector_type(4))) float f32x4;

// RNE fp32 -> bf16 (bit trick; matches HW cvt for normal values)
static __device__ __forceinline__ short f2bf(float x) {
    unsigned u = __float_as_uint(x);
    unsigned r = u + 0x7fff + ((u >> 16) & 1);
    return (short)(r >> 16);
}
static __device__ __forceinline__ float bf2f(short s) {
    return __uint_as_float(((unsigned)(unsigned short)s) << 16);
}

// Fused: centroid fp32 -> (hi,lo) bf16 split + c2 row norms + counter zero.
__global__ void prep_kernel(const float* __restrict__ c, short* __restrict__ ch,
                            short* __restrict__ cl, float* __restrict__ c2,
                            int K, int* __restrict__ counter) {
    int t = blockIdx.x * blockDim.x + threadIdx.x;
    if (t == 0) *counter = 0;
    const int nf4 = K * (D / 4);
    if (t < nf4) {
        float4 v = ((const float4*)c)[t];
        short hx = f2bf(v.x), hy = f2bf(v.y), hz = f2bf(v.z), hw = f2bf(v.w);
        ((short4*)ch)[t] = make_short4(hx, hy, hz, hw);
        ((short4*)cl)[t] = make_short4(f2bf(v.x - bf2f(hx)), f2bf(v.y - bf2f(hy)),
                                       f2bf(v.z - bf2f(hz)), f2bf(v.w - bf2f(hw)));
    }
    if (t < K) {
        const float4* cp = (const float4*)(c + (size_t)t * D);
        float s = 0.f;
#pragma unroll
        for (int i = 0; i < D / 4; ++i) {
            float4 v = cp[i];
            s += v.x * v.x; s += v.y * v.y; s += v.z * v.z; s += v.w * v.w;
        }
        c2[t] = s;
    }
}

// Pass 1: split-bf16 MFMA distance scan, top-2 tracking, K split over
// blockIdx.y. Depth-2 prefetch via two NAMED buffers + manual 2x unroll
// (round-8's pb[slot] dynamic index demoted the ring to scratch -> 10.9 GB
// HBM spill traffic. Named scalars cannot be demoted.)
// score(n,k) = c2[k] - 2*dot(a,c); dot ~= ah.ch + ah.cl + al.ch
__global__ __launch_bounds__(256, 4) void pass1_kernel(
    const float* __restrict__ action, const short* __restrict__ ch,
    const short* __restrict__ cl, const float* __restrict__ c2,
    float4* __restrict__ cand, int N, int K) {
    const int tid  = threadIdx.x;
    const int wv   = tid >> 6;
    const int lane = tid & 63;
    const int col  = lane & 15;
    const int quad = lane >> 4;
    const int m0   = blockIdx.x * 128 + wv * 32;
    const int KC   = K / KSPLIT;
    const int k0   = blockIdx.y * KC;

    // A fragments: fp32 -> (hi, lo) bf16 in registers, once.
    bf16x8 ah[2][2], al[2][2];
#pragma unroll
    for (int mi = 0; mi < 2; ++mi) {
        const float* arow = action + (size_t)(m0 + mi * 16 + col) * D;
#pragma unroll
        for (int ks = 0; ks < 2; ++ks) {
            const float* src = arow + ks * 32 + quad * 8;
            bf16x8 h, l;
#pragma unroll
            for (int j = 0; j < 8; ++j) {
                float x = src[j];
                short hs = f2bf(x);
                h[j] = hs;
                l[j] = f2bf(x - bf2f(hs));
            }
            ah[mi][ks] = h;
            al[mi][ks] = l;
        }
    }

    float b1[8], b2[8];
    int   bk[8];
#pragma unroll
    for (int e = 0; e < 8; ++e) {
        b1[e] = __builtin_inff(); b2[e] = __builtin_inff(); bk[e] = k0;
    }

    const int T = KC / 16;   // 64 iterations, even

    // two named prefetch buffers (A = even iters, B = odd iters)
    const size_t colbase = (size_t)col * D + quad * 8;
    const short* chp = ch + colbase;
    const short* clp = cl + colbase;

    bf16x8 Ah0, Ah1, Al0, Al1; float Ac;
    bf16x8 Bh0, Bh1, Bl0, Bl1; float Bc;
    {
        const size_t kb0 = (size_t)(k0 + 0) * D;
        const size_t kb1 = (size_t)(k0 + 16) * D;
        Ah0 = *(const bf16x8*)(chp + kb0);
        Ah1 = *(const bf16x8*)(chp + kb0 + 32);
        Al0 = *(const bf16x8*)(clp + kb0);
        Al1 = *(const bf16x8*)(clp + kb0 + 32);
        Ac  = c2[k0 + col];
        Bh0 = *(const bf16x8*)(chp + kb1);
        Bh1 = *(const bf16x8*)(chp + kb1 + 32);
        Bl0 = *(const bf16x8*)(clp + kb1);
        Bl1 = *(const bf16x8*)(clp + kb1 + 32);
        Bc  = c2[k0 + 16 + col];
    }

#define FOLD(acc_, cc_, kk_)                                                 \
    _Pragma("unroll") for (int r = 0; r < 4; ++r) {                          \
        const int e = mi * 4 + r;                                            \
        const float s = fmaf(-2.f, (acc_)[r], (cc_));                        \
        b2[e] = __builtin_amdgcn_fmed3f(s, b1[e], b2[e]);                    \
        const bool better = s < b1[e];                                       \
        b1[e] = fminf(b1[e], s);                                             \
        bk[e] = better ? (kk_) : bk[e];                                      \
    }

#define MFMA6(bh0_, bh1_, bl0_, bl1_)                                        \
    acc = __builtin_amdgcn_mfma_f32_16x16x32_bf16(al[mi][0], bh0_, acc, 0, 0, 0); \
    acc = __builtin_amdgcn_mfma_f32_16x16x32_bf16(ah[mi][0], bl0_, acc, 0, 0, 0); \
    acc = __builtin_amdgcn_mfma_f32_16x16x32_bf16(ah[mi][0], bh0_, acc, 0, 0, 0); \
    acc = __builtin_amdgcn_mfma_f32_16x16x32_bf16(al[mi][1], bh1_, acc, 0, 0, 0); \
    acc = __builtin_amdgcn_mfma_f32_16x16x32_bf16(ah[mi][1], bl1_, acc, 0, 0, 0); \
    acc = __builtin_amdgcn_mfma_f32_16x16x32_bf16(ah[mi][1], bh1_, acc, 0, 0, 0);

    for (int i = 0; i < T; i += 2) {
        // ---- even iteration: consume A, refill A with iter i+2
        {
            bf16x8 bh0 = Ah0, bh1 = Ah1, bl0 = Al0, bl1 = Al1;
            const float cc = Ac;
            const int   k  = k0 + i * 16 + col;
            if (i + 2 < T) {
                const size_t kb = (size_t)(k0 + (i + 2) * 16) * D;
                Ah0 = *(const bf16x8*)(chp + kb);
                Ah1 = *(const bf16x8*)(chp + kb + 32);
                Al0 = *(const bf16x8*)(clp + kb);
                Al1 = *(const bf16x8*)(clp + kb + 32);
                Ac  = c2[k0 + (i + 2) * 16 + col];
            }
#pragma unroll
            for (int mi = 0; mi < 2; ++mi) {
                f32x4 acc = {0.f, 0.f, 0.f, 0.f};
                MFMA6(bh0, bh1, bl0, bl1)
                FOLD(acc, cc, k)
            }
        }
        // ---- odd iteration: consume B, refill B with iter i+3
        {
            bf16x8 bh0 = Bh0, bh1 = Bh1, bl0 = Bl0, bl1 = Bl1;
            const float cc = Bc;
            const int   k  = k0 + (i + 1) * 16 + col;
            if (i + 3 < T) {
                const size_t kb = (size_t)(k0 + (i + 3) * 16) * D;
                Bh0 = *(const bf16x8*)(chp + kb);
                Bh1 = *(const bf16x8*)(chp + kb + 32);
                Bl0 = *(const bf16x8*)(clp + kb);
                Bl1 = *(const bf16x8*)(clp + kb + 32);
                Bc  = c2[k0 + (i + 3) * 16 + col];
            }
#pragma unroll
            for (int mi = 0; mi < 2; ++mi) {
                f32x4 acc = {0.f, 0.f, 0.f, 0.f};
                MFMA6(bh0, bh1, bl0, bl1)
                FOLD(acc, cc, k)
            }
        }
    }
#undef MFMA6
#undef FOLD

    // cross-lane top-2 merge over the 16 centroid columns
#pragma unroll
    for (int off = 1; off < 16; off <<= 1) {
#pragma unroll
        for (int e = 0; e < 8; ++e) {
            float o1 = __shfl_xor(b1[e], off, 64);
            float o2 = __shfl_xor(b2[e], off, 64);
            int   ok = __shfl_xor(bk[e], off, 64);
            bool take = (o1 < b1[e]) || (o1 == b1[e] && ok < bk[e]);
            float nb2 = take ? fminf(b1[e], o2) : fminf(b2[e], o1);
            b1[e] = take ? o1 : b1[e];
            bk[e] = take ? ok : bk[e];
            b2[e] = nb2;
        }
    }

    if (col == 0) {
#pragma unroll
        for (int e = 0; e < 8; ++e) {
            const int mi = e >> 2, r = e & 3;
            const int p = m0 + mi * 16 + quad * 4 + r;
            cand[(size_t)blockIdx.y * N + p] =
                make_float4(b1[e], b2[e], (float)bk[e], 0.f);
        }
    }
}

// Fused merge + bin write + ambiguity flag + exact fp32 residual.
__global__ __launch_bounds__(256) void resflag_kernel(
    const float* __restrict__ action, const float* __restrict__ centroids,
    const float4* __restrict__ cand, float* __restrict__ out_bin,
    float* __restrict__ out_res, int* __restrict__ counter,
    int* __restrict__ flags, int N) {
    int n = blockIdx.x * blockDim.x + threadIdx.x;
    if (n >= N) return;
    float4 v0 = cand[n];
    float4 v1 = cand[(size_t)N + n];
    float b1, b2; int bk;
    if (v1.x < v0.x) { b1 = v1.x; bk = (int)v1.z; b2 = fminf(v0.x, v1.y); }
    else             { b1 = v0.x; bk = (int)v0.z; b2 = fminf(v1.x, v0.y); }
    out_bin[n] = (float)bk;
    if (b2 - b1 < EPS) {
        int idx = atomicAdd(counter, 1);
        flags[idx] = n;
    }
    const float4* ap = (const float4*)(action + (size_t)n * D);
    const float4* cp = (const float4*)(centroids + (size_t)bk * D);
    float4*       rp = (float4*)(out_res + (size_t)n * D);
#pragma unroll
    for (int i = 0; i < D / 4; ++i) {
        float4 a = ap[i], c = cp[i];
        rp[i] = make_float4(a.x - c.x, a.y - c.y, a.z - c.z, a.w - c.w);
    }
}

// Exact fp32 rescan for flagged points. Block-per-point grid-stride,
// 4 interleaved dot accumulators for ILP.
__global__ __launch_bounds__(256) void exact_kernel(
    const float* __restrict__ action, const float* __restrict__ centroids,
    const float* __restrict__ c2, const int* __restrict__ counter,
    const int* __restrict__ flags, float* __restrict__ out_bin,
    float* __restrict__ out_res, int K) {
    __shared__ float4 sa[D / 4];
    __shared__ float  swv[4];
    __shared__ int    swk[4];
    __shared__ int    s_bk;
    const int count = *counter;
    const int tid = threadIdx.x, lane = tid & 63, wid = tid >> 6;
    for (int i = blockIdx.x; i < count; i += gridDim.x) {
        const int n = flags[i];
        __syncthreads();
        if (tid < D / 4) sa[tid] = ((const float4*)(action + (size_t)n * D))[tid];
        __syncthreads();
        float best = __builtin_inff();
        int bbk = 0x7fffffff;
        for (int k = tid; k < K; k += 256) {
            const float4* cr = (const float4*)(centroids + (size_t)k * D);
            float d0 = 0.f, d1 = 0.f, d2 = 0.f, d3 = 0.f;
#pragma unroll
            for (int q = 0; q < 4; ++q) {
                float4 a0 = sa[q * 4 + 0], c0 = cr[q * 4 + 0];
                float4 a1 = sa[q * 4 + 1], c1 = cr[q * 4 + 1];
                float4 a2 = sa[q * 4 + 2], c2v = cr[q * 4 + 2];
                float4 a3 = sa[q * 4 + 3], c3 = cr[q * 4 + 3];
                d0 = fmaf(a0.x, c0.x, d0); d0 = fmaf(a0.y, c0.y, d0);
                d0 = fmaf(a0.z, c0.z, d0); d0 = fmaf(a0.w, c0.w, d0);
                d1 = fmaf(a1.x, c1.x, d1); d1 = fmaf(a1.y, c1.y, d1);
                d1 = fmaf(a1.z, c1.z, d1); d1 = fmaf(a1.w, c1.w, d1);
                d2 = fmaf(a2.x, c2v.x, d2); d2 = fmaf(a2.y, c2v.y, d2);
                d2 = fmaf(a2.z, c2v.z, d2); d2 = fmaf(a2.w, c2v.w, d2);
                d3 = fmaf(a3.x, c3.x, d3); d3 = fmaf(a3.y, c3.y, d3);
                d3 = fmaf(a3.z, c3.z, d3); d3 = fmaf(a3.w, c3.w, d3);
            }
            float dot = (d0 + d1) + (d2 + d3);
            float s = fmaf(-2.f, dot, c2[k]);
            if (s < best) { best = s; bbk = k; }  // ascending k: first-min
        }
#pragma unroll
        for (int off = 32; off > 0; off >>= 1) {
            float ov = __shfl_down(best, off, 64);
            int   ok = __shfl_down(bbk, off, 64);
            if (ov < best || (ov == best && ok < bbk)) { best = ov; bbk = ok; }
        }
        if (lane == 0) { swv[wid] = best; swk[wid] = bbk; }
        __syncthreads();
        if (tid == 0) {
            float bb = swv[0]; int bki = swk[0];
#pragma unroll
            for (int t = 1; t < 4; ++t)
                if (swv[t] < bb || (swv[t] == bb && swk[t] < bki)) {
                    bb = swv[t]; bki = swk[t];
                }
            out_bin[n] = (float)bki;
            s_bk = bki;
        }
        __syncthreads();
        if (tid < D / 4) {
            float4 a = sa[tid];
            float4 c = ((const float4*)(centroids + (size_t)s_bk * D))[tid];
            ((float4*)(out_res + (size_t)n * D))[tid] =
                make_float4(a.x - c.x, a.y - c.y, a.z - c.z, a.w - c.w);
        }
    }
}

extern "C" void kernel_launch(void* const* d_in, const int* in_sizes, int n_in,
                              void* d_out, int out_size, void* d_ws, size_t ws_size,
                              hipStream_t stream) {
    const float* action    = (const float*)d_in[0];  // [N, 64]
    const float* centroids = (const float*)d_in[1];  // [K, 64]
    const int N = in_sizes[0] / D;  // 65536
    const int K = in_sizes[1] / D;  // 2048

    float* out_bin = (float*)d_out;      // N floats: argmin index
    float* out_res = (float*)d_out + N;  // N*D residuals

    // ws layout (~2.9 MB)
    char* w = (char*)d_ws;
    float*  c2      = (float*)w;                       // 8 KB
    int*    counter = (int*)(w + 8192);                // 4 B (padded to 256)
    int*    flags   = (int*)(w + 8448);                // N*4 = 256 KB
    short*  ch      = (short*)(w + 8448 + 262144);     // K*D*2 = 256 KB
    short*  cl      = ch + (size_t)K * D;              // 256 KB
    float4* cand    = (float4*)(cl + (size_t)K * D);   // KSPLIT*N*16 = 2 MB

    prep_kernel<<<(K * (D / 4) + 255) / 256, 256, 0, stream>>>(centroids, ch, cl,
                                                               c2, K, counter);
    dim3 g1(N / 128, KSPLIT);
    pass1_kernel<<<g1, 256, 0, stream>>>(action, ch, cl, c2, cand, N, K);
    resflag_kernel<<<(N + 255) / 256, 256, 0, stream>>>(action, centroids, cand,
                                                        out_bin, out_res, counter,
                                                        flags, N);
    exact_kernel<<<2048, 256, 0, stream>>>(action, centroids, c2, counter, flags,
                                           out_bin, out_res, K);
}

// Round 10
// 173.180 us; speedup vs baseline: 42.9895x; 1.8000x over previous
//
#include <hip/hip_runtime.h>

#define D 64
#define EPS 0.006f
#define KSPLIT 2
#define CHUNK 64   // centroids per LDS tile

typedef __attribute__((ext_vector_type(8))) short bf16x8;
typedef __attribute__((ext_vector_type(4))) float f32x4;

// RNE fp32 -> bf16 (bit trick; matches HW cvt for normal values)
static __device__ __forceinline__ short f2bf(float x) {
    unsigned u = __float_as_uint(x);
    unsigned r = u + 0x7fff + ((u >> 16) & 1);
    return (short)(r >> 16);
}
static __device__ __forceinline__ float bf2f(short s) {
    return __uint_as_float(((unsigned)(unsigned short)s) << 16);
}

// async global->LDS, 16 B per lane. LDS dst = wave-uniform base + lane*16.
// CK-style addrspace reinterpret (generic LDS ptr low 32 bits = AS3 offset).
static __device__ __forceinline__ void async16(const void* g, void* l) {
    __builtin_amdgcn_global_load_lds(
        (const __attribute__((address_space(1))) unsigned int*)((unsigned long long)g),
        (__attribute__((address_space(3))) unsigned int*)((unsigned int)(unsigned long long)l),
        16, 0, 0);
}

// prep: build pre-swizzled bf16 hi/lo centroid images + c2 + zero counter.
// Image: per 64-centroid chunk (8192 B), frag for centroid k=(kc*16+col),
// d-octet (ks*32+quad*8) lives at ((kc*2+ks)*64 + quad*16 + col)*16 B.
// After a flat lane-contiguous LDS copy, lane (quad*16+col) ds_reads its MFMA
// B-fragment at seg + lane*16 (bank-optimal).
__global__ void prep_kernel(const float* __restrict__ c, short* __restrict__ chs,
                            short* __restrict__ cls, float* __restrict__ c2,
                            int K, int* __restrict__ counter) {
    int t = blockIdx.x * blockDim.x + threadIdx.x;
    if (t == 0) *counter = 0;
    const int nfr = K * 8;
    if (t < nfr) {
        const int k = t >> 3, f = t & 7;
        const int ks = f >> 2, quad = f & 3;
        const int chunk = k >> 6, kc = (k >> 4) & 3, col = k & 15;
        const size_t off = (size_t)chunk * 4096 +
                           (size_t)(((kc * 2 + ks) * 64 + quad * 16 + col) * 8);
        const float* src = c + (size_t)k * D + f * 8;
        bf16x8 h, l;
#pragma unroll
        for (int j = 0; j < 8; ++j) {
            float x = src[j];
            short hs = f2bf(x);
            h[j] = hs;
            l[j] = f2bf(x - bf2f(hs));
        }
        *(bf16x8*)(chs + off) = h;
        *(bf16x8*)(cls + off) = l;
    }
    if (t < K) {
        const float4* cp = (const float4*)(c + (size_t)t * D);
        float s = 0.f;
#pragma unroll
        for (int i = 0; i < D / 4; ++i) {
            float4 v = cp[i];
            s += v.x * v.x; s += v.y * v.y; s += v.z * v.z; s += v.w * v.w;
        }
        c2[t] = s;
    }
}

// Pass 1: split-bf16 MFMA scan, B staged through double-buffered LDS via
// async global_load_lds (register prefetch spilled in r8/r9 — LDS frags are
// transient ds_read->MFMA operands, nothing for the allocator to demote).
// score(n,k) = c2[k] - 2*dot(a,c); dot ~= ah.ch + ah.cl + al.ch
__global__ __launch_bounds__(256, 4) void pass1_kernel(
    const float* __restrict__ action, const short* __restrict__ chs,
    const short* __restrict__ cls, const float* __restrict__ c2,
    float4* __restrict__ cand, int N, int K) {
    __shared__ short ldsbuf[2][2][4096];   // [dbuf][hi/lo][8 KB] = 32 KB

    const int tid  = threadIdx.x;
    const int wv   = tid >> 6;
    const int lane = tid & 63;
    const int col  = lane & 15;
    const int quad = lane >> 4;
    const int m0   = blockIdx.x * 128 + wv * 32;
    const int KC   = K / KSPLIT;
    const int k0   = blockIdx.y * KC;
    const int NC   = KC / CHUNK;           // 16
    const int ch0  = k0 >> 6;              // first chunk id

#define STAGE(cid_, buf_)                                                     \
    {                                                                         \
        const size_t gb = (size_t)(cid_) * 4096;                              \
        _Pragma("unroll") for (int r = 0; r < 2; ++r) {                       \
            const int el = (r * 256 + tid) * 8;                               \
            const int lb = (r * 256 + wv * 64) * 8;                           \
            async16(chs + gb + el, &ldsbuf[buf_][0][lb]);                     \
            async16(cls + gb + el, &ldsbuf[buf_][1][lb]);                     \
        }                                                                     \
    }

    // stage chunk 0 (flight overlaps A-fragment conversion below)
    STAGE(ch0, 0)

    // A fragments: fp32 -> (hi, lo) bf16 in registers, once.
    bf16x8 ah[2][2], al[2][2];
#pragma unroll
    for (int mi = 0; mi < 2; ++mi) {
        const float* arow = action + (size_t)(m0 + mi * 16 + col) * D;
#pragma unroll
        for (int ks = 0; ks < 2; ++ks) {
            const float* src = arow + ks * 32 + quad * 8;
            bf16x8 h, l;
#pragma unroll
            for (int j = 0; j < 8; ++j) {
                float x = src[j];
                short hs = f2bf(x);
                h[j] = hs;
                l[j] = f2bf(x - bf2f(hs));
            }
            ah[mi][ks] = h;
            al[mi][ks] = l;
        }
    }

    float b1[8], b2[8];
    int   bk[8];
#pragma unroll
    for (int e = 0; e < 8; ++e) {
        b1[e] = __builtin_inff(); b2[e] = __builtin_inff(); bk[e] = k0;
    }

#define FOLD(acc_, cc_, kk_)                                                  \
    _Pragma("unroll") for (int r = 0; r < 4; ++r) {                           \
        const int e = mi * 4 + r;                                             \
        const float s = fmaf(-2.f, (acc_)[r], (cc_));                         \
        b2[e] = __builtin_amdgcn_fmed3f(s, b1[e], b2[e]);                     \
        const bool better = s < b1[e];                                        \
        b1[e] = fminf(b1[e], s);                                              \
        bk[e] = better ? (kk_) : bk[e];                                       \
    }

#define KCBODY(kc_, cc_)                                                      \
    {                                                                         \
        bf16x8 bh0 = *(const bf16x8*)&ldsbuf[buf][0][(((kc_)*2+0)*64+lane)*8];\
        bf16x8 bh1 = *(const bf16x8*)&ldsbuf[buf][0][(((kc_)*2+1)*64+lane)*8];\
        bf16x8 bl0 = *(const bf16x8*)&ldsbuf[buf][1][(((kc_)*2+0)*64+lane)*8];\
        bf16x8 bl1 = *(const bf16x8*)&ldsbuf[buf][1][(((kc_)*2+1)*64+lane)*8];\
        const int k = kbase + (kc_)*16 + col;                                 \
        _Pragma("unroll") for (int mi = 0; mi < 2; ++mi) {                    \
            f32x4 acc = {0.f, 0.f, 0.f, 0.f};                                 \
            acc = __builtin_amdgcn_mfma_f32_16x16x32_bf16(al[mi][0], bh0, acc, 0, 0, 0); \
            acc = __builtin_amdgcn_mfma_f32_16x16x32_bf16(ah[mi][0], bl0, acc, 0, 0, 0); \
            acc = __builtin_amdgcn_mfma_f32_16x16x32_bf16(ah[mi][0], bh0, acc, 0, 0, 0); \
            acc = __builtin_amdgcn_mfma_f32_16x16x32_bf16(al[mi][1], bh1, acc, 0, 0, 0); \
            acc = __builtin_amdgcn_mfma_f32_16x16x32_bf16(ah[mi][1], bl1, acc, 0, 0, 0); \
            acc = __builtin_amdgcn_mfma_f32_16x16x32_bf16(ah[mi][1], bh1, acc, 0, 0, 0); \
            FOLD(acc, cc_, k)                                                 \
        }                                                                     \
    }

    for (int c = 0; c < NC; ++c) {
        const int buf = c & 1;
        __syncthreads();                    // chunk c resident in ldsbuf[buf]
        const int kbase = k0 + c * CHUNK;
        const float cc0 = c2[kbase +  0 + col];
        const float cc1 = c2[kbase + 16 + col];
        const float cc2 = c2[kbase + 32 + col];
        const float cc3 = c2[kbase + 48 + col];
        if (c + 1 < NC) STAGE(ch0 + c + 1, buf ^ 1)   // in flight under compute
        KCBODY(0, cc0)
        KCBODY(1, cc1)
        KCBODY(2, cc2)
        KCBODY(3, cc3)
    }
#undef KCBODY
#undef FOLD
#undef STAGE

    // cross-lane top-2 merge over the 16 centroid columns
#pragma unroll
    for (int off = 1; off < 16; off <<= 1) {
#pragma unroll
        for (int e = 0; e < 8; ++e) {
            float o1 = __shfl_xor(b1[e], off, 64);
            float o2 = __shfl_xor(b2[e], off, 64);
            int   ok = __shfl_xor(bk[e], off, 64);
            bool take = (o1 < b1[e]) || (o1 == b1[e] && ok < bk[e]);
            float nb2 = take ? fminf(b1[e], o2) : fminf(b2[e], o1);
            b1[e] = take ? o1 : b1[e];
            bk[e] = take ? ok : bk[e];
            b2[e] = nb2;
        }
    }

    if (col == 0) {
#pragma unroll
        for (int e = 0; e < 8; ++e) {
            const int mi = e >> 2, r = e & 3;
            const int p = m0 + mi * 16 + quad * 4 + r;
            cand[(size_t)blockIdx.y * N + p] =
                make_float4(b1[e], b2[e], (float)bk[e], 0.f);
        }
    }
}

// Fused merge + bin write + ambiguity flag + exact fp32 residual.
__global__ __launch_bounds__(256) void resflag_kernel(
    const float* __restrict__ action, const float* __restrict__ centroids,
    const float4* __restrict__ cand, float* __restrict__ out_bin,
    float* __restrict__ out_res, int* __restrict__ counter,
    int* __restrict__ flags, int N) {
    int n = blockIdx.x * blockDim.x + threadIdx.x;
    if (n >= N) return;
    float4 v0 = cand[n];
    float4 v1 = cand[(size_t)N + n];
    float b1, b2; int bk;
    if (v1.x < v0.x) { b1 = v1.x; bk = (int)v1.z; b2 = fminf(v0.x, v1.y); }
    else             { b1 = v0.x; bk = (int)v0.z; b2 = fminf(v1.x, v0.y); }
    out_bin[n] = (float)bk;
    if (b2 - b1 < EPS) {
        int idx = atomicAdd(counter, 1);
        flags[idx] = n;
    }
    const float4* ap = (const float4*)(action + (size_t)n * D);
    const float4* cp = (const float4*)(centroids + (size_t)bk * D);
    float4*       rp = (float4*)(out_res + (size_t)n * D);
#pragma unroll
    for (int i = 0; i < D / 4; ++i) {
        float4 a = ap[i], c = cp[i];
        rp[i] = make_float4(a.x - c.x, a.y - c.y, a.z - c.z, a.w - c.w);
    }
}

// Exact fp32 rescan for flagged points. Block-per-point grid-stride,
// 4 interleaved dot accumulators for ILP.
__global__ __launch_bounds__(256) void exact_kernel(
    const float* __restrict__ action, const float* __restrict__ centroids,
    const float* __restrict__ c2, const int* __restrict__ counter,
    const int* __restrict__ flags, float* __restrict__ out_bin,
    float* __restrict__ out_res, int K) {
    __shared__ float4 sa[D / 4];
    __shared__ float  swv[4];
    __shared__ int    swk[4];
    __shared__ int    s_bk;
    const int count = *counter;
    const int tid = threadIdx.x, lane = tid & 63, wid = tid >> 6;
    for (int i = blockIdx.x; i < count; i += gridDim.x) {
        const int n = flags[i];
        __syncthreads();
        if (tid < D / 4) sa[tid] = ((const float4*)(action + (size_t)n * D))[tid];
        __syncthreads();
        float best = __builtin_inff();
        int bbk = 0x7fffffff;
        for (int k = tid; k < K; k += 256) {
            const float4* cr = (const float4*)(centroids + (size_t)k * D);
            float d0 = 0.f, d1 = 0.f, d2 = 0.f, d3 = 0.f;
#pragma unroll
            for (int q = 0; q < 4; ++q) {
                float4 a0 = sa[q * 4 + 0], c0 = cr[q * 4 + 0];
                float4 a1 = sa[q * 4 + 1], c1 = cr[q * 4 + 1];
                float4 a2 = sa[q * 4 + 2], c2v = cr[q * 4 + 2];
                float4 a3 = sa[q * 4 + 3], c3 = cr[q * 4 + 3];
                d0 = fmaf(a0.x, c0.x, d0); d0 = fmaf(a0.y, c0.y, d0);
                d0 = fmaf(a0.z, c0.z, d0); d0 = fmaf(a0.w, c0.w, d0);
                d1 = fmaf(a1.x, c1.x, d1); d1 = fmaf(a1.y, c1.y, d1);
                d1 = fmaf(a1.z, c1.z, d1); d1 = fmaf(a1.w, c1.w, d1);
                d2 = fmaf(a2.x, c2v.x, d2); d2 = fmaf(a2.y, c2v.y, d2);
                d2 = fmaf(a2.z, c2v.z, d2); d2 = fmaf(a2.w, c2v.w, d2);
                d3 = fmaf(a3.x, c3.x, d3); d3 = fmaf(a3.y, c3.y, d3);
                d3 = fmaf(a3.z, c3.z, d3); d3 = fmaf(a3.w, c3.w, d3);
            }
            float dot = (d0 + d1) + (d2 + d3);
            float s = fmaf(-2.f, dot, c2[k]);
            if (s < best) { best = s; bbk = k; }  // ascending k: first-min
        }
#pragma unroll
        for (int off = 32; off > 0; off >>= 1) {
            float ov = __shfl_down(best, off, 64);
            int   ok = __shfl_down(bbk, off, 64);
            if (ov < best || (ov == best && ok < bbk)) { best = ov; bbk = ok; }
        }
        if (lane == 0) { swv[wid] = best; swk[wid] = bbk; }
        __syncthreads();
        if (tid == 0) {
            float bb = swv[0]; int bki = swk[0];
#pragma unroll
            for (int t = 1; t < 4; ++t)
                if (swv[t] < bb || (swv[t] == bb && swk[t] < bki)) {
                    bb = swv[t]; bki = swk[t];
                }
            out_bin[n] = (float)bki;
            s_bk = bki;
        }
        __syncthreads();
        if (tid < D / 4) {
            float4 a = sa[tid];
            float4 c = ((const float4*)(centroids + (size_t)s_bk * D))[tid];
            ((float4*)(out_res + (size_t)n * D))[tid] =
                make_float4(a.x - c.x, a.y - c.y, a.z - c.z, a.w - c.w);
        }
    }
}

extern "C" void kernel_launch(void* const* d_in, const int* in_sizes, int n_in,
                              void* d_out, int out_size, void* d_ws, size_t ws_size,
                              hipStream_t stream) {
    const float* action    = (const float*)d_in[0];  // [N, 64]
    const float* centroids = (const float*)d_in[1];  // [K, 64]
    const int N = in_sizes[0] / D;  // 65536
    const int K = in_sizes[1] / D;  // 2048

    float* out_bin = (float*)d_out;      // N floats: argmin index
    float* out_res = (float*)d_out + N;  // N*D residuals

    // ws layout (~2.9 MB)
    char* w = (char*)d_ws;
    float*  c2      = (float*)w;                       // 8 KB
    int*    counter = (int*)(w + 8192);                // 4 B (padded to 256)
    int*    flags   = (int*)(w + 8448);                // N*4 = 256 KB
    short*  chs     = (short*)(w + 8448 + 262144);     // K*D*2 = 256 KB (swizzled)
    short*  cls     = chs + (size_t)K * D;             // 256 KB (swizzled)
    float4* cand    = (float4*)(cls + (size_t)K * D);  // KSPLIT*N*16 = 2 MB

    prep_kernel<<<(K * 8 + 255) / 256, 256, 0, stream>>>(centroids, chs, cls,
                                                         c2, K, counter);
    dim3 g1(N / 128, KSPLIT);
    pass1_kernel<<<g1, 256, 0, stream>>>(action, chs, cls, c2, cand, N, K);
    resflag_kernel<<<(N + 255) / 256, 256, 0, stream>>>(action, centroids, cand,
                                                        out_bin, out_res, counter,
                                                        flags, N);
    exact_kernel<<<2048, 256, 0, stream>>>(action, centroids, c2, counter, flags,
                                           out_bin, out_res, K);
}